// Round 8
// baseline (412.270 us; speedup 1.0000x reference)
//
#include <hip/hip_runtime.h>

typedef __attribute__((ext_vector_type(8))) short short8;
typedef __attribute__((ext_vector_type(8))) unsigned short us8;
typedef __attribute__((ext_vector_type(4))) unsigned short us4;
typedef __attribute__((ext_vector_type(4))) float f32x4;

static __device__ __forceinline__ unsigned short f2bf(float f) {
  union { float f; unsigned u; } c; c.f = f;
  unsigned r = (c.u + 0x7FFFu + ((c.u >> 16) & 1u)) >> 16;
  return (unsigned short)r;
}
static __device__ __forceinline__ float b2f(unsigned short h) {
  union { unsigned u; float f; } c; c.u = ((unsigned)h) << 16; return c.f;
}

static __device__ __forceinline__ void gll16(const unsigned short* g, unsigned short* l) {
  __builtin_amdgcn_global_load_lds(
      (const __attribute__((address_space(1))) unsigned int*)g,
      (__attribute__((address_space(3))) unsigned int*)l, 16, 0, 0);
}

// ---- wv, wp -> bf16
__global__ __launch_bounds__(256) void conv_k(
    const float* __restrict__ wv, const float* __restrict__ wp,
    unsigned short* __restrict__ wvb, unsigned short* __restrict__ wpb)
{
  int i4 = (blockIdx.x * 256 + threadIdx.x) * 4;
  const float* src;
  unsigned short* dst;
  if (i4 < 262144) { src = wv + i4; dst = wvb + i4; }
  else             { src = wp + (i4 - 262144); dst = wpb + (i4 - 262144); }
  f32x4 v = *(const f32x4*)src;
  us4 o;
  #pragma unroll
  for (int j = 0; j < 4; ++j) o[j] = f2bf(v[j]);
  *(us4*)dst = o;
}

// ---- transpose wq,wk (f32 [512][512]) -> wqT,wkT (bf16 [c][o])
__global__ __launch_bounds__(256) void tk(
    const float* __restrict__ wq, const float* __restrict__ wk,
    unsigned short* __restrict__ wqT, unsigned short* __restrict__ wkT)
{
  __shared__ float L[64][65];
  const float* src = blockIdx.z ? wk : wq;
  unsigned short* dst = blockIdx.z ? wkT : wqT;
  const int ro = blockIdx.x * 64, co = blockIdx.y * 64;
  const int tid = threadIdx.x;
  #pragma unroll
  for (int p = 0; p < 4; ++p) {
    int lin = p * 1024 + tid * 4;
    int r = lin >> 6, cl = lin & 63;
    *(f32x4*)&L[r][cl] = *(const f32x4*)(src + (size_t)(ro + r) * 512 + co + cl);
  }
  __syncthreads();
  #pragma unroll
  for (int p = 0; p < 4; ++p) {
    int lin = p * 1024 + tid * 4;
    int rr = lin >> 6, cc = lin & 63;
    us4 o;
    #pragma unroll
    for (int j = 0; j < 4; ++j) o[j] = f2bf(L[cc + j][rr]);
    *(us4*)(dst + (size_t)(co + rr) * 512 + ro + cc) = o;
  }
}

// ---- w2b[c] = sum_o bq[o] * wk[o][c]  (from wkT rows)
__global__ __launch_bounds__(256) void w2b_k(
    const unsigned short* __restrict__ wkT, const float* __restrict__ bq,
    float* __restrict__ w2b)
{
  const int wv_ = threadIdx.x >> 6, lane = threadIdx.x & 63;
  for (int i = 0; i < 16; ++i) {
    const int c = blockIdx.x * 64 + i * 4 + wv_;
    us8 kv = *(const us8*)(wkT + (size_t)c * 512 + lane * 8);
    float s = 0.f;
    #pragma unroll
    for (int j = 0; j < 8; ++j) s += b2f(kv[j]) * bq[lane * 8 + j];
    #pragma unroll
    for (int o = 32; o; o >>= 1) s += __shfl_xor(s, o);
    if (lane == 0) w2b[c] = s;
  }
}

// ---- uflat[r] = sum_c hT[r][c] * w2b[c]
__global__ __launch_bounds__(256) void gemv_u(
    const unsigned short* __restrict__ hT, const float* __restrict__ w2b,
    float* __restrict__ u)
{
  const int row = blockIdx.x * 4 + (threadIdx.x >> 6);
  const int lane = threadIdx.x & 63;
  us8 hv = *(const us8*)(hT + (size_t)row * 512 + lane * 8);
  f32x4 w0 = *(const f32x4*)(w2b + lane * 8);
  f32x4 w1 = *(const f32x4*)(w2b + lane * 8 + 4);
  float s = 0.f;
  #pragma unroll
  for (int j = 0; j < 4; ++j) s += b2f(hv[j]) * w0[j];
  #pragma unroll
  for (int j = 0; j < 4; ++j) s += b2f(hv[4 + j]) * w1[j];
  #pragma unroll
  for (int o = 32; o; o >>= 1) s += __shfl_xor(s, o);
  if (lane == 0) u[row] = s;
}

// ---- GroupNorm -> hT [b][s=256][c=512] bf16
__global__ __launch_bounds__(512) void gn_k(
    const float* __restrict__ x, const float* __restrict__ gw,
    const float* __restrict__ gb, unsigned short* __restrict__ hT)
{
  __shared__ unsigned short tile[32][256];
  __shared__ float rs[2][4][2];
  const int b = blockIdx.x >> 4, gp = blockIdx.x & 15;
  const int tid = threadIdx.x;
  const int sub = tid >> 8;
  const int t = tid & 255;
  const int g = gp * 2 + sub;
  const float* xp = x + ((size_t)b * 512 + g * 16) * 256;
  f32x4 vals[4];
  float s = 0.f, s2 = 0.f;
  #pragma unroll
  for (int j = 0; j < 4; ++j) {
    f32x4 v = *(const f32x4*)(xp + j * 1024 + t * 4);
    vals[j] = v;
    s  += v[0] + v[1] + v[2] + v[3];
    s2 += v[0]*v[0] + v[1]*v[1] + v[2]*v[2] + v[3]*v[3];
  }
  #pragma unroll
  for (int o = 32; o; o >>= 1) { s += __shfl_xor(s, o); s2 += __shfl_xor(s2, o); }
  if ((t & 63) == 0) { rs[sub][t >> 6][0] = s; rs[sub][t >> 6][1] = s2; }
  __syncthreads();
  s  = rs[sub][0][0] + rs[sub][1][0] + rs[sub][2][0] + rs[sub][3][0];
  s2 = rs[sub][0][1] + rs[sub][1][1] + rs[sub][2][1] + rs[sub][3][1];
  const float mean = s * (1.f / 4096.f);
  const float var  = s2 * (1.f / 4096.f) - mean * mean;
  const float rstd = rsqrtf(var + 1e-5f);
  #pragma unroll
  for (int j = 0; j < 4; ++j) {
    const int cl = j * 4 + (t >> 6);
    const int c = g * 16 + cl;
    const float sc = gw[c] * rstd;
    const float sh = gb[c] - mean * sc;
    f32x4 v = vals[j];
    us4 o;
    #pragma unroll
    for (int q = 0; q < 4; ++q) o[q] = f2bf(v[q] * sc + sh);
    *(us4*)&tile[sub * 16 + cl][(t & 63) * 4] = o;
  }
  __syncthreads();
  const int srow = tid >> 1, half = tid & 1;
  us8 o0, o1;
  #pragma unroll
  for (int c = 0; c < 8; ++c) o0[c] = tile[half * 16 + c][srow];
  #pragma unroll
  for (int c = 0; c < 8; ++c) o1[c] = tile[half * 16 + 8 + c][srow];
  unsigned short* dst = hT + ((size_t)b * 256 + srow) * 512 + gp * 32 + half * 16;
  *(us8*)dst = o0;
  *(us8*)(dst + 8) = o1;
}

// ---- pipelined B^T-form GEMM: C[bz][m][n] = sum_k A[m][k]*B[n][k]
// EPI 0: normal epilogue. EPI 1: flat T1/v: bn<512 -> bf16 to Cv; bn>=512 -> LDS-transpose
//        to Cv2 = v[b][c][s] with bias bv. EPI 2: f32 transpose + resid -> out[b][c][s].
template<int BM, int BN, int MI, int TPB, int NWN, int NTT,
         int BIAS_MODE, bool OUT_F32, bool HAS_RESID, bool NFAST, int EPI>
__global__ __launch_bounds__(TPB, 2) void gemmp_k(
    const unsigned short* __restrict__ A, long long sAb, int lda,
    const unsigned short* __restrict__ B, long long sBb, int ldb,
    void* __restrict__ Cv, long long sCb, int ldc,
    const float* __restrict__ bias, const float* __restrict__ resid,
    void* __restrict__ Cv2)
{
  constexpr int CA = BM * 8 / TPB;
  constexpr int CB = BN * 8 / TPB;
  static_assert(EPI == 0 || (BM == 256 && BN == 256 && TPB == 512), "flat epilogue geometry");
  __shared__ unsigned short SMEM[2 * BM * 64 + 2 * BN * 64];
  unsigned short* AsBase = SMEM;
  unsigned short* BsBase = SMEM + 2 * BM * 64;
  const int tid = threadIdx.x;
  const int bz = blockIdx.z;
  const int bm = (NFAST ? blockIdx.y : blockIdx.x) * BM;
  const int bn = (NFAST ? blockIdx.x : blockIdx.y) * BN;
  const int lane = tid & 63, w = tid >> 6;
  const int wr = w / NWN, wc = w % NWN;
  const int lr = lane & 15, lg = lane >> 4;
  const int csw = lr & 7;
  const int ko0 = (lg ^ csw) * 8;
  const int ko1 = ((4 + lg) ^ csw) * 8;

  const unsigned short* aSrc[CA]; int aOff[CA];
  const unsigned short* bSrc[CB]; int bOff[CB];
  #pragma unroll
  for (int p = 0; p < CA; ++p) {
    const int id = p * TPB + tid;
    const int row = id >> 3, cc = (id & 7) ^ (row & 7);
    aSrc[p] = A + (size_t)bz * sAb + (size_t)(bm + row) * lda + cc * 8;
    aOff[p] = id * 8;
  }
  #pragma unroll
  for (int p = 0; p < CB; ++p) {
    const int id = p * TPB + tid;
    const int row = id >> 3, cc = (id & 7) ^ (row & 7);
    bSrc[p] = B + (size_t)bz * sBb + (size_t)(bn + row) * ldb + cc * 8;
    bOff[p] = id * 8;
  }

  f32x4 acc[MI][4];
  #pragma unroll
  for (int i = 0; i < MI; ++i)
    #pragma unroll
    for (int j = 0; j < 4; ++j) acc[i][j] = (f32x4){0.f, 0.f, 0.f, 0.f};

  #pragma unroll
  for (int p = 0; p < CA; ++p) gll16(aSrc[p], &AsBase[aOff[p]]);
  #pragma unroll
  for (int p = 0; p < CB; ++p) gll16(bSrc[p], &BsBase[bOff[p]]);
  asm volatile("s_waitcnt vmcnt(0)" ::: "memory");
  __builtin_amdgcn_s_barrier();

  #pragma unroll 2
  for (int t = 0; t < NTT; ++t) {
    if (t + 1 < NTT) {
      const int k1 = (t + 1) * 64, sl = (t + 1) & 1;
      #pragma unroll
      for (int p = 0; p < CA; ++p) gll16(aSrc[p] + k1, &AsBase[sl * BM * 64 + aOff[p]]);
      #pragma unroll
      for (int p = 0; p < CB; ++p) gll16(bSrc[p] + k1, &BsBase[sl * BN * 64 + bOff[p]]);
    }
    const unsigned short* At = &AsBase[(t & 1) * BM * 64];
    const unsigned short* Bt = &BsBase[(t & 1) * BN * 64];
    short8 bf[4][2];
    #pragma unroll
    for (int nj = 0; nj < 4; ++nj) {
      bf[nj][0] = *(const short8*)(Bt + (wc * 64 + nj * 16 + lr) * 64 + ko0);
      bf[nj][1] = *(const short8*)(Bt + (wc * 64 + nj * 16 + lr) * 64 + ko1);
    }
    #pragma unroll
    for (int h = 0; h < MI / 4; ++h) {
      short8 af[4][2];
      #pragma unroll
      for (int mi = 0; mi < 4; ++mi) {
        const int rr = wr * (MI * 16) + h * 64 + mi * 16 + lr;
        af[mi][0] = *(const short8*)(At + rr * 64 + ko0);
        af[mi][1] = *(const short8*)(At + rr * 64 + ko1);
      }
      __builtin_amdgcn_s_setprio(1);
      #pragma unroll
      for (int mi = 0; mi < 4; ++mi)
        #pragma unroll
        for (int nj = 0; nj < 4; ++nj) {
          acc[h * 4 + mi][nj] = __builtin_amdgcn_mfma_f32_16x16x32_bf16(af[mi][0], bf[nj][0], acc[h * 4 + mi][nj], 0, 0, 0);
          acc[h * 4 + mi][nj] = __builtin_amdgcn_mfma_f32_16x16x32_bf16(af[mi][1], bf[nj][1], acc[h * 4 + mi][nj], 0, 0, 0);
        }
      __builtin_amdgcn_s_setprio(0);
    }
    if (t + 1 < NTT) {
      asm volatile("s_waitcnt vmcnt(0)" ::: "memory");
      __builtin_amdgcn_s_barrier();
    }
  }

  if (EPI == 1 && bn >= 512) {
    // ---- vT transpose epilogue: m-tile == batch; write v[b][c][s] bf16, bias bv
    __syncthreads();
    char* T = (char*)SMEM;   // [256 c][256 s] bf16, XOR-swizzled
    #pragma unroll
    for (int mi = 0; mi < MI; ++mi) {
      const int rowb = wr * (MI * 16) + mi * 16 + lg * 4;
      #pragma unroll
      for (int ni = 0; ni < 4; ++ni) {
        const int col = wc * 64 + ni * 16 + lr;
        const float bb = bias[bn - 512 + col];
        us4 pk;
        #pragma unroll
        for (int r = 0; r < 4; ++r) pk[r] = f2bf(acc[mi][ni][r] + bb);
        const int bo = (col * 512 + rowb * 2) ^ ((col & 7) << 4);
        *(us4*)(T + bo) = pk;
      }
    }
    __syncthreads();
    const int b = bm >> 8;
    const int c = tid >> 1, s0 = (tid & 1) * 128;
    unsigned short* dst = (unsigned short*)Cv2 +
        ((size_t)b * 512 + (bn - 512) + c) * 256 + s0;
    #pragma unroll
    for (int j = 0; j < 16; ++j) {
      const int s = s0 + j * 8;
      const int bo = (c * 512 + s * 2) ^ ((c & 7) << 4);
      *(us8*)(dst + j * 8) = *(const us8*)(T + bo);
    }
  } else if (EPI == 2) {
    // ---- f32 transpose + resid epilogue -> out[b][c][s]
    const int b = bm >> 8;
    char* T = (char*)SMEM;
    #pragma unroll
    for (int hh = 0; hh < 2; ++hh) {
      __syncthreads();
      if ((wc >> 1) == hh) {
        #pragma unroll
        for (int mi = 0; mi < MI; ++mi) {
          const int rowb = wr * (MI * 16) + mi * 16 + lg * 4;
          #pragma unroll
          for (int ni = 0; ni < 4; ++ni) {
            const int col = wc * 64 + ni * 16 + lr;
            const int cl = col - hh * 128;
            const float bb = bias[bn + col];
            f32x4 pv;
            #pragma unroll
            for (int r = 0; r < 4; ++r) pv[r] = acc[mi][ni][r] + bb;
            const int bo = (cl * 1024 + rowb * 4) ^ ((cl & 7) << 4);
            *(f32x4*)(T + bo) = pv;
          }
        }
      }
      __syncthreads();
      const int cl = tid >> 2, q = tid & 3;
      const size_t gr = ((size_t)b * 512 + bn + hh * 128 + cl) * 256;
      float* outp = (float*)Cv + gr;
      const float* xp = resid + gr;
      #pragma unroll
      for (int j = 0; j < 16; ++j) {
        const int s = q * 64 + j * 4;
        const int bo = (cl * 1024 + s * 4) ^ ((cl & 7) << 4);
        f32x4 v = *(const f32x4*)(T + bo);
        f32x4 xv = *(const f32x4*)(xp + s);
        v += xv;
        *(f32x4*)(outp + s) = v;
      }
    }
  } else {
    #pragma unroll
    for (int mi = 0; mi < MI; ++mi) {
      #pragma unroll
      for (int r = 0; r < 4; ++r) {
        const int rowc = bm + wr * (MI * 16) + mi * 16 + lg * 4 + r;
        const float bv_ = (BIAS_MODE == 1) ? bias[rowc] : 0.f;
        #pragma unroll
        for (int ni = 0; ni < 4; ++ni) {
          const int col = bn + wc * 64 + ni * 16 + lr;
          float vv = acc[mi][ni][r] + bv_;
          if (BIAS_MODE == 2) vv += bias[col];
          const size_t idx = (size_t)bz * sCb + (size_t)rowc * ldc + col;
          if (HAS_RESID) vv += resid[idx];
          if (OUT_F32) ((float*)Cv)[idx] = vv;
          else ((unsigned short*)Cv)[idx] = f2bf(vv);
        }
      }
    }
  }
}

// ---- 256x256 GEMM + per-col u bias + fused row-softmax (G2)
template<int NT>
__global__ __launch_bounds__(512, 2) void gemm3_k(
    const unsigned short* __restrict__ A, long long sAb, int lda,
    const unsigned short* __restrict__ B, long long sBb, int ldb,
    unsigned short* __restrict__ Cb_, long long sCb, int ldc,
    const float* __restrict__ u)
{
  __shared__ unsigned short As[4][8192];
  __shared__ unsigned short Bs[4][8192];
  const int tid = threadIdx.x;
  const int bz = blockIdx.z;
  const int lane = tid & 63, w = tid >> 6;
  const int wr = w >> 2, wc = w & 3;
  const int lr = lane & 15, lg = lane >> 4;
  const int csw = lr & 7;
  const int ko0 = (lg ^ csw) * 8;
  const int ko1 = ((4 + lg) ^ csw) * 8;

  const int rl = tid >> 3;
  const int gc = (tid & 7) ^ (rl & 7);
  const unsigned short* pA = A + (size_t)bz * sAb + (size_t)rl * lda + gc * 8;
  const unsigned short* pB = B + (size_t)bz * sBb + (size_t)rl * ldb + gc * 8;

  auto stageA = [&](int t, int h) {
    const unsigned short* s = pA + (size_t)h * 128 * lda + t * 64;
    unsigned short* d = &As[(2 * t + h) & 3][tid * 8];
    gll16(s, d);
    gll16(s + (size_t)64 * lda, d + 4096);
  };
  auto stageB = [&](int t, int h) {
    const unsigned short* s = pB + (size_t)h * 128 * ldb + t * 64;
    unsigned short* d = &Bs[(2 * t + h) & 3][tid * 8];
    gll16(s, d);
    gll16(s + (size_t)64 * ldb, d + 4096);
  };

  f32x4 acc[8][4];
  #pragma unroll
  for (int i = 0; i < 8; ++i)
    #pragma unroll
    for (int j = 0; j < 4; ++j) acc[i][j] = (f32x4){0.f, 0.f, 0.f, 0.f};

  stageA(0, 0); stageA(0, 1); stageB(0, 0); stageB(0, 1);
  stageB(1, 0); stageA(1, 0); stageA(1, 1);
  asm volatile("s_waitcnt vmcnt(6)" ::: "memory");
  __builtin_amdgcn_s_barrier();

  for (int t = 0; t < NT; ++t) {
    const unsigned short* sA = &As[(2 * t + wr) & 3][0];
    const unsigned short* sB = &Bs[(2 * t + (wc >> 1)) & 3][0];
    const int bc = (wc & 1) * 64;
    short8 af[4][2], bf0[2][2], bf1[2][2];

    #pragma unroll
    for (int mi = 0; mi < 4; ++mi) {
      af[mi][0] = *(const short8*)(sA + (mi * 16 + lr) * 64 + ko0);
      af[mi][1] = *(const short8*)(sA + (mi * 16 + lr) * 64 + ko1);
    }
    #pragma unroll
    for (int nj = 0; nj < 2; ++nj) {
      bf0[nj][0] = *(const short8*)(sB + (bc + nj * 16 + lr) * 64 + ko0);
      bf0[nj][1] = *(const short8*)(sB + (bc + nj * 16 + lr) * 64 + ko1);
    }
    if (t + 1 < NT) stageB(t + 1, 1);
    __builtin_amdgcn_s_barrier();
    __builtin_amdgcn_s_setprio(1);
    #pragma unroll
    for (int mi = 0; mi < 4; ++mi)
      #pragma unroll
      for (int nj = 0; nj < 2; ++nj) {
        acc[mi][nj] = __builtin_amdgcn_mfma_f32_16x16x32_bf16(af[mi][0], bf0[nj][0], acc[mi][nj], 0, 0, 0);
        acc[mi][nj] = __builtin_amdgcn_mfma_f32_16x16x32_bf16(af[mi][1], bf0[nj][1], acc[mi][nj], 0, 0, 0);
      }
    __builtin_amdgcn_s_setprio(0);
    __builtin_amdgcn_s_barrier();

    #pragma unroll
    for (int nj = 0; nj < 2; ++nj) {
      bf1[nj][0] = *(const short8*)(sB + (bc + 32 + nj * 16 + lr) * 64 + ko0);
      bf1[nj][1] = *(const short8*)(sB + (bc + 32 + nj * 16 + lr) * 64 + ko1);
    }
    __builtin_amdgcn_s_barrier();
    __builtin_amdgcn_s_setprio(1);
    #pragma unroll
    for (int mi = 0; mi < 4; ++mi)
      #pragma unroll
      for (int nj = 0; nj < 2; ++nj) {
        acc[mi][2 + nj] = __builtin_amdgcn_mfma_f32_16x16x32_bf16(af[mi][0], bf1[nj][0], acc[mi][2 + nj], 0, 0, 0);
        acc[mi][2 + nj] = __builtin_amdgcn_mfma_f32_16x16x32_bf16(af[mi][1], bf1[nj][1], acc[mi][2 + nj], 0, 0, 0);
      }
    __builtin_amdgcn_s_setprio(0);
    __builtin_amdgcn_s_barrier();

    #pragma unroll
    for (int mi = 0; mi < 4; ++mi) {
      af[mi][0] = *(const short8*)(sA + (64 + mi * 16 + lr) * 64 + ko0);
      af[mi][1] = *(const short8*)(sA + (64 + mi * 16 + lr) * 64 + ko1);
    }
    if (t + 2 < NT) stageB(t + 2, 0);
    __builtin_amdgcn_s_barrier();
    __builtin_amdgcn_s_setprio(1);
    #pragma unroll
    for (int mi = 0; mi < 4; ++mi)
      #pragma unroll
      for (int nj = 0; nj < 2; ++nj) {
        acc[4 + mi][nj] = __builtin_amdgcn_mfma_f32_16x16x32_bf16(af[mi][0], bf0[nj][0], acc[4 + mi][nj], 0, 0, 0);
        acc[4 + mi][nj] = __builtin_amdgcn_mfma_f32_16x16x32_bf16(af[mi][1], bf0[nj][1], acc[4 + mi][nj], 0, 0, 0);
      }
    __builtin_amdgcn_s_setprio(0);
    __builtin_amdgcn_s_barrier();

    if (t + 2 < NT) { stageA(t + 2, 0); stageA(t + 2, 1); }
    __builtin_amdgcn_s_barrier();
    __builtin_amdgcn_s_setprio(1);
    #pragma unroll
    for (int mi = 0; mi < 4; ++mi)
      #pragma unroll
      for (int nj = 0; nj < 2; ++nj) {
        acc[4 + mi][2 + nj] = __builtin_amdgcn_mfma_f32_16x16x32_bf16(af[mi][0], bf1[nj][0], acc[4 + mi][2 + nj], 0, 0, 0);
        acc[4 + mi][2 + nj] = __builtin_amdgcn_mfma_f32_16x16x32_bf16(af[mi][1], bf1[nj][1], acc[4 + mi][2 + nj], 0, 0, 0);
      }
    __builtin_amdgcn_s_setprio(0);
    if (t == NT - 2)      asm volatile("s_waitcnt vmcnt(0)" ::: "memory");
    else if (t < NT - 2)  asm volatile("s_waitcnt vmcnt(6)" ::: "memory");
    __builtin_amdgcn_s_barrier();
  }

  // add per-column u (exact bias-term of QK^T after softmax-cancellation)
  float uv[4];
  #pragma unroll
  for (int ni = 0; ni < 4; ++ni) uv[ni] = u[bz * 256 + wc * 64 + ni * 16 + lr];
  #pragma unroll
  for (int mi = 0; mi < 8; ++mi)
    #pragma unroll
    for (int ni = 0; ni < 4; ++ni)
      #pragma unroll
      for (int r = 0; r < 4; ++r) acc[mi][ni][r] += uv[ni];

  const float SC = 0.044194173824159216f;
  float* redm = (float*)&As[0][0];
  float* reds = redm + 1024;
  float rmax[8][4];
  #pragma unroll
  for (int mi = 0; mi < 8; ++mi)
    #pragma unroll
    for (int r = 0; r < 4; ++r) {
      float m = fmaxf(fmaxf(acc[mi][0][r], acc[mi][1][r]),
                      fmaxf(acc[mi][2][r], acc[mi][3][r]));
      #pragma unroll
      for (int o = 1; o <= 8; o <<= 1) m = fmaxf(m, __shfl_xor(m, o));
      rmax[mi][r] = m;
    }
  __syncthreads();
  if (lr == 0) {
    #pragma unroll
    for (int mi = 0; mi < 8; ++mi)
      #pragma unroll
      for (int r = 0; r < 4; ++r)
        redm[(wr * 128 + mi * 16 + lg * 4 + r) * 4 + wc] = rmax[mi][r];
  }
  __syncthreads();
  float rsum[8][4];
  #pragma unroll
  for (int mi = 0; mi < 8; ++mi)
    #pragma unroll
    for (int r = 0; r < 4; ++r) {
      const int row = wr * 128 + mi * 16 + lg * 4 + r;
      f32x4 q = *(const f32x4*)&redm[row * 4];
      const float m = fmaxf(fmaxf(q[0], q[1]), fmaxf(q[2], q[3]));
      float s = 0.f;
      #pragma unroll
      for (int ni = 0; ni < 4; ++ni) {
        float e = __expf((acc[mi][ni][r] - m) * SC);
        acc[mi][ni][r] = e;
        s += e;
      }
      #pragma unroll
      for (int o = 1; o <= 8; o <<= 1) s += __shfl_xor(s, o);
      rsum[mi][r] = s;
    }
  if (lr == 0) {
    #pragma unroll
    for (int mi = 0; mi < 8; ++mi)
      #pragma unroll
      for (int r = 0; r < 4; ++r)
        reds[(wr * 128 + mi * 16 + lg * 4 + r) * 4 + wc] = rsum[mi][r];
  }
  __syncthreads();
  unsigned short* Cb = Cb_ + (size_t)bz * sCb;
  #pragma unroll
  for (int mi = 0; mi < 8; ++mi)
    #pragma unroll
    for (int r = 0; r < 4; ++r) {
      const int row = wr * 128 + mi * 16 + lg * 4 + r;
      f32x4 q = *(const f32x4*)&reds[row * 4];
      const float inv = 1.f / (q[0] + q[1] + q[2] + q[3]);
      #pragma unroll
      for (int ni = 0; ni < 4; ++ni) {
        const int col = wc * 64 + ni * 16 + lr;
        Cb[(size_t)row * ldc + col] = f2bf(acc[mi][ni][r] * inv);
      }
    }
}

extern "C" void kernel_launch(void* const* d_in, const int* in_sizes, int n_in,
                              void* d_out, int out_size, void* d_ws, size_t ws_size,
                              hipStream_t stream)
{
  const float* x   = (const float*)d_in[0];
  const float* gnw = (const float*)d_in[1];
  const float* gnb = (const float*)d_in[2];
  const float* wq  = (const float*)d_in[3];
  const float* bq  = (const float*)d_in[4];
  const float* wk  = (const float*)d_in[5];
  // const float* bk = (const float*)d_in[6];   // cancels in softmax (row-constant terms)
  const float* wv  = (const float*)d_in[7];
  const float* bv  = (const float*)d_in[8];
  const float* wp  = (const float*)d_in[9];
  const float* bp  = (const float*)d_in[10];
  float* out = (float*)d_out;

  char* ws = (char*)d_ws;
  unsigned short* wcomb = (unsigned short*)(ws);                  // [1024][512] bf16: W2T | wvb
  unsigned short* wvb   = wcomb + 262144;
  unsigned short* wpb   = (unsigned short*)(ws + 1048576);        // [512][512] bf16
  unsigned short* wqT   = (unsigned short*)(ws + 1572864);        // [512][512] bf16 (c-major)
  unsigned short* wkT   = (unsigned short*)(ws + 2097152);        // [512][512] bf16 (c-major)
  float*          w2b   = (float*)(ws + 2621440);                 // [512] f32
  float*          uflat = (float*)(ws + 2623488);                 // [65536] f32
  unsigned short* hT    = (unsigned short*)(ws + 2885632);        // 65536x512 bf16 (reused as oT)
  unsigned short* T1    = (unsigned short*)(ws + 69994496ull);    // 65536x512 bf16
  unsigned short* v     = (unsigned short*)(ws + 137103360ull);   // B*512*256 bf16
  unsigned short* attb  = (unsigned short*)(ws + 204212224ull);   // B*256*256 bf16
  unsigned short* oT    = hT;

  conv_k<<<512, 256, 0, stream>>>(wv, wp, wvb, wpb);
  tk<<<dim3(8, 8, 2), 256, 0, stream>>>(wq, wk, wqT, wkT);
  w2b_k<<<8, 256, 0, stream>>>(wkT, bq, w2b);
  // W2T[d][c] = sum_o wk[o][d]*wq[o][c]  (A=wkT, B=wqT)
  gemmp_k<128, 128, 4, 256, 2, 8, 0, false, false, false, 0><<<dim3(4, 4, 1), 256, 0, stream>>>(
      wkT, 0, 512, wqT, 0, 512, wcomb, 0, 512, nullptr, nullptr, nullptr);
  gn_k<<<4096, 512, 0, stream>>>(x, gnw, gnb, hT);
  // G1: flat [65536 x 1024 x 512]: cols<512 -> T1 (=hT*W2T^T); cols>=512 -> v[b][c][s]+bv
  gemmp_k<256, 256, 8, 512, 4, 8, 0, false, false, true, 1><<<dim3(4, 256, 1), 512, 0, stream>>>(
      hT, 0, 512, wcomb, 0, 512, T1, 0, 512, bv, nullptr, v);
  gemv_u<<<16384, 256, 0, stream>>>(hT, w2b, uflat);
  // G2+softmax: attb[b][s][t] = softmax_t((T1 hT^T + 1 u^T) / sqrt(512))
  gemm3_k<8><<<dim3(1, 1, 256), 512, 0, stream>>>(
      T1, 131072, 512, hT, 131072, 512, attb, 65536, 256, uflat);
  // G3: oT[b][t][c] = attb[b] x v[b]^T
  gemmp_k<128, 128, 4, 256, 2, 4, 0, false, false, false, 0><<<dim3(2, 4, 256), 256, 0, stream>>>(
      attb, 65536, 256, v, 131072, 256, oT, 131072, 512, nullptr, nullptr, nullptr);
  // G4flat: out[b][c][s] = x + wp*o + bp (transpose+resid epilogue)
  gemmp_k<256, 256, 8, 512, 4, 8, 2, false, false, true, 2><<<dim3(2, 256, 1), 512, 0, stream>>>(
      oT, 0, 512, wpb, 0, 512, out, 0, 256, bp, x, nullptr);
}

// Round 9
// 367.020 us; speedup vs baseline: 1.1233x; 1.1233x over previous
//
#include <hip/hip_runtime.h>

typedef __attribute__((ext_vector_type(8))) short short8;
typedef __attribute__((ext_vector_type(8))) unsigned short us8;
typedef __attribute__((ext_vector_type(4))) unsigned short us4;
typedef __attribute__((ext_vector_type(4))) float f32x4;

static __device__ __forceinline__ unsigned short f2bf(float f) {
  union { float f; unsigned u; } c; c.f = f;
  unsigned r = (c.u + 0x7FFFu + ((c.u >> 16) & 1u)) >> 16;
  return (unsigned short)r;
}
static __device__ __forceinline__ float b2f(unsigned short h) {
  union { unsigned u; float f; } c; c.u = ((unsigned)h) << 16; return c.f;
}

static __device__ __forceinline__ void gll16(const unsigned short* g, unsigned short* l) {
  __builtin_amdgcn_global_load_lds(
      (const __attribute__((address_space(1))) unsigned int*)g,
      (__attribute__((address_space(3))) unsigned int*)l, 16, 0, 0);
}

// ---- wv, wp -> bf16
__global__ __launch_bounds__(256) void conv_k(
    const float* __restrict__ wv, const float* __restrict__ wp,
    unsigned short* __restrict__ wvb, unsigned short* __restrict__ wpb)
{
  int i4 = (blockIdx.x * 256 + threadIdx.x) * 4;
  const float* src;
  unsigned short* dst;
  if (i4 < 262144) { src = wv + i4; dst = wvb + i4; }
  else             { src = wp + (i4 - 262144); dst = wpb + (i4 - 262144); }
  f32x4 v = *(const f32x4*)src;
  us4 o;
  #pragma unroll
  for (int j = 0; j < 4; ++j) o[j] = f2bf(v[j]);
  *(us4*)dst = o;
}

// ---- transpose wq,wk (f32 [512][512]) -> wqT,wkT (bf16 [c][o])
__global__ __launch_bounds__(256) void tk(
    const float* __restrict__ wq, const float* __restrict__ wk,
    unsigned short* __restrict__ wqT, unsigned short* __restrict__ wkT)
{
  __shared__ float L[64][65];
  const float* src = blockIdx.z ? wk : wq;
  unsigned short* dst = blockIdx.z ? wkT : wqT;
  const int ro = blockIdx.x * 64, co = blockIdx.y * 64;
  const int tid = threadIdx.x;
  #pragma unroll
  for (int p = 0; p < 4; ++p) {
    int lin = p * 1024 + tid * 4;
    int r = lin >> 6, cl = lin & 63;
    *(f32x4*)&L[r][cl] = *(const f32x4*)(src + (size_t)(ro + r) * 512 + co + cl);
  }
  __syncthreads();
  #pragma unroll
  for (int p = 0; p < 4; ++p) {
    int lin = p * 1024 + tid * 4;
    int rr = lin >> 6, cc = lin & 63;
    us4 o;
    #pragma unroll
    for (int j = 0; j < 4; ++j) o[j] = f2bf(L[cc + j][rr]);
    *(us4*)(dst + (size_t)(co + rr) * 512 + ro + cc) = o;
  }
}

// ---- w2b[c] = sum_o bq[o] * wk[o][c]
__global__ __launch_bounds__(256) void w2b_k(
    const unsigned short* __restrict__ wkT, const float* __restrict__ bq,
    float* __restrict__ w2b)
{
  const int wv_ = threadIdx.x >> 6, lane = threadIdx.x & 63;
  for (int i = 0; i < 16; ++i) {
    const int c = blockIdx.x * 64 + i * 4 + wv_;
    us8 kv = *(const us8*)(wkT + (size_t)c * 512 + lane * 8);
    float s = 0.f;
    #pragma unroll
    for (int j = 0; j < 8; ++j) s += b2f(kv[j]) * bq[lane * 8 + j];
    #pragma unroll
    for (int o = 32; o; o >>= 1) s += __shfl_xor(s, o);
    if (lane == 0) w2b[c] = s;
  }
}

// ---- uflat[r] = sum_c hT[r][c] * w2b[c]
__global__ __launch_bounds__(256) void gemv_u(
    const unsigned short* __restrict__ hT, const float* __restrict__ w2b,
    float* __restrict__ u)
{
  const int row = blockIdx.x * 4 + (threadIdx.x >> 6);
  const int lane = threadIdx.x & 63;
  us8 hv = *(const us8*)(hT + (size_t)row * 512 + lane * 8);
  f32x4 w0 = *(const f32x4*)(w2b + lane * 8);
  f32x4 w1 = *(const f32x4*)(w2b + lane * 8 + 4);
  float s = 0.f;
  #pragma unroll
  for (int j = 0; j < 4; ++j) s += b2f(hv[j]) * w0[j];
  #pragma unroll
  for (int j = 0; j < 4; ++j) s += b2f(hv[4 + j]) * w1[j];
  #pragma unroll
  for (int o = 32; o; o >>= 1) s += __shfl_xor(s, o);
  if (lane == 0) u[row] = s;
}

// ---- GroupNorm -> hT [b][s=256][c=512] bf16
__global__ __launch_bounds__(512) void gn_k(
    const float* __restrict__ x, const float* __restrict__ gw,
    const float* __restrict__ gb, unsigned short* __restrict__ hT)
{
  __shared__ unsigned short tile[32][256];
  __shared__ float rs[2][4][2];
  const int b = blockIdx.x >> 4, gp = blockIdx.x & 15;
  const int tid = threadIdx.x;
  const int sub = tid >> 8;
  const int t = tid & 255;
  const int g = gp * 2 + sub;
  const float* xp = x + ((size_t)b * 512 + g * 16) * 256;
  f32x4 vals[4];
  float s = 0.f, s2 = 0.f;
  #pragma unroll
  for (int j = 0; j < 4; ++j) {
    f32x4 v = *(const f32x4*)(xp + j * 1024 + t * 4);
    vals[j] = v;
    s  += v[0] + v[1] + v[2] + v[3];
    s2 += v[0]*v[0] + v[1]*v[1] + v[2]*v[2] + v[3]*v[3];
  }
  #pragma unroll
  for (int o = 32; o; o >>= 1) { s += __shfl_xor(s, o); s2 += __shfl_xor(s2, o); }
  if ((t & 63) == 0) { rs[sub][t >> 6][0] = s; rs[sub][t >> 6][1] = s2; }
  __syncthreads();
  s  = rs[sub][0][0] + rs[sub][1][0] + rs[sub][2][0] + rs[sub][3][0];
  s2 = rs[sub][0][1] + rs[sub][1][1] + rs[sub][2][1] + rs[sub][3][1];
  const float mean = s * (1.f / 4096.f);
  const float var  = s2 * (1.f / 4096.f) - mean * mean;
  const float rstd = rsqrtf(var + 1e-5f);
  #pragma unroll
  for (int j = 0; j < 4; ++j) {
    const int cl = j * 4 + (t >> 6);
    const int c = g * 16 + cl;
    const float sc = gw[c] * rstd;
    const float sh = gb[c] - mean * sc;
    f32x4 v = vals[j];
    us4 o;
    #pragma unroll
    for (int q = 0; q < 4; ++q) o[q] = f2bf(v[q] * sc + sh);
    *(us4*)&tile[sub * 16 + cl][(t & 63) * 4] = o;
  }
  __syncthreads();
  const int srow = tid >> 1, half = tid & 1;
  us8 o0, o1;
  #pragma unroll
  for (int c = 0; c < 8; ++c) o0[c] = tile[half * 16 + c][srow];
  #pragma unroll
  for (int c = 0; c < 8; ++c) o1[c] = tile[half * 16 + 8 + c][srow];
  unsigned short* dst = hT + ((size_t)b * 256 + srow) * 512 + gp * 32 + half * 16;
  *(us8*)dst = o0;
  *(us8*)(dst + 8) = o1;
}

// ---- pipelined B^T-form GEMM, plain epilogue only:
// C[bz][m][n] = sum_k A[m][k]*B[n][k] (+bias row/col) (+resid)
template<int BM, int BN, int MI, int TPB, int NWN, int NTT,
         int BIAS_MODE, bool OUT_F32, bool HAS_RESID, bool NFAST>
__global__ __launch_bounds__(TPB, 2) void gemmp_k(
    const unsigned short* __restrict__ A, long long sAb, int lda,
    const unsigned short* __restrict__ B, long long sBb, int ldb,
    void* __restrict__ Cv, long long sCb, int ldc,
    const float* __restrict__ bias, const float* __restrict__ resid)
{
  constexpr int CA = BM * 8 / TPB;
  constexpr int CB = BN * 8 / TPB;
  __shared__ unsigned short SMEM[2 * BM * 64 + 2 * BN * 64];
  unsigned short* AsBase = SMEM;
  unsigned short* BsBase = SMEM + 2 * BM * 64;
  const int tid = threadIdx.x;
  const int bz = blockIdx.z;
  const int bm = (NFAST ? blockIdx.y : blockIdx.x) * BM;
  const int bn = (NFAST ? blockIdx.x : blockIdx.y) * BN;
  const int lane = tid & 63, w = tid >> 6;
  const int wr = w / NWN, wc = w % NWN;
  const int lr = lane & 15, lg = lane >> 4;
  const int csw = lr & 7;
  const int ko0 = (lg ^ csw) * 8;
  const int ko1 = ((4 + lg) ^ csw) * 8;

  const unsigned short* aSrc[CA]; int aOff[CA];
  const unsigned short* bSrc[CB]; int bOff[CB];
  #pragma unroll
  for (int p = 0; p < CA; ++p) {
    const int id = p * TPB + tid;
    const int row = id >> 3, cc = (id & 7) ^ (row & 7);
    aSrc[p] = A + (size_t)bz * sAb + (size_t)(bm + row) * lda + cc * 8;
    aOff[p] = id * 8;
  }
  #pragma unroll
  for (int p = 0; p < CB; ++p) {
    const int id = p * TPB + tid;
    const int row = id >> 3, cc = (id & 7) ^ (row & 7);
    bSrc[p] = B + (size_t)bz * sBb + (size_t)(bn + row) * ldb + cc * 8;
    bOff[p] = id * 8;
  }

  f32x4 acc[MI][4];
  #pragma unroll
  for (int i = 0; i < MI; ++i)
    #pragma unroll
    for (int j = 0; j < 4; ++j) acc[i][j] = (f32x4){0.f, 0.f, 0.f, 0.f};

  #pragma unroll
  for (int p = 0; p < CA; ++p) gll16(aSrc[p], &AsBase[aOff[p]]);
  #pragma unroll
  for (int p = 0; p < CB; ++p) gll16(bSrc[p], &BsBase[bOff[p]]);
  asm volatile("s_waitcnt vmcnt(0)" ::: "memory");
  __builtin_amdgcn_s_barrier();

  #pragma unroll 2
  for (int t = 0; t < NTT; ++t) {
    if (t + 1 < NTT) {
      const int k1 = (t + 1) * 64, sl = (t + 1) & 1;
      #pragma unroll
      for (int p = 0; p < CA; ++p) gll16(aSrc[p] + k1, &AsBase[sl * BM * 64 + aOff[p]]);
      #pragma unroll
      for (int p = 0; p < CB; ++p) gll16(bSrc[p] + k1, &BsBase[sl * BN * 64 + bOff[p]]);
    }
    const unsigned short* At = &AsBase[(t & 1) * BM * 64];
    const unsigned short* Bt = &BsBase[(t & 1) * BN * 64];
    short8 bf[4][2];
    #pragma unroll
    for (int nj = 0; nj < 4; ++nj) {
      bf[nj][0] = *(const short8*)(Bt + (wc * 64 + nj * 16 + lr) * 64 + ko0);
      bf[nj][1] = *(const short8*)(Bt + (wc * 64 + nj * 16 + lr) * 64 + ko1);
    }
    #pragma unroll
    for (int h = 0; h < MI / 4; ++h) {
      short8 af[4][2];
      #pragma unroll
      for (int mi = 0; mi < 4; ++mi) {
        const int rr = wr * (MI * 16) + h * 64 + mi * 16 + lr;
        af[mi][0] = *(const short8*)(At + rr * 64 + ko0);
        af[mi][1] = *(const short8*)(At + rr * 64 + ko1);
      }
      __builtin_amdgcn_s_setprio(1);
      #pragma unroll
      for (int mi = 0; mi < 4; ++mi)
        #pragma unroll
        for (int nj = 0; nj < 4; ++nj) {
          acc[h * 4 + mi][nj] = __builtin_amdgcn_mfma_f32_16x16x32_bf16(af[mi][0], bf[nj][0], acc[h * 4 + mi][nj], 0, 0, 0);
          acc[h * 4 + mi][nj] = __builtin_amdgcn_mfma_f32_16x16x32_bf16(af[mi][1], bf[nj][1], acc[h * 4 + mi][nj], 0, 0, 0);
        }
      __builtin_amdgcn_s_setprio(0);
    }
    if (t + 1 < NTT) {
      asm volatile("s_waitcnt vmcnt(0)" ::: "memory");
      __builtin_amdgcn_s_barrier();
    }
  }

  #pragma unroll
  for (int mi = 0; mi < MI; ++mi) {
    #pragma unroll
    for (int r = 0; r < 4; ++r) {
      const int rowc = bm + wr * (MI * 16) + mi * 16 + lg * 4 + r;
      const float bv_ = (BIAS_MODE == 1) ? bias[rowc] : 0.f;
      #pragma unroll
      for (int ni = 0; ni < 4; ++ni) {
        const int col = bn + wc * 64 + ni * 16 + lr;
        float vv = acc[mi][ni][r] + bv_;
        if (BIAS_MODE == 2) vv += bias[col];
        const size_t idx = (size_t)bz * sCb + (size_t)rowc * ldc + col;
        if (HAS_RESID) vv += resid[idx];
        if (OUT_F32) ((float*)Cv)[idx] = vv;
        else ((unsigned short*)Cv)[idx] = f2bf(vv);
      }
    }
  }
}

// ---- 256x256 GEMM + per-col u bias + fused row-softmax (G2)
template<int NT>
__global__ __launch_bounds__(512, 2) void gemm3_k(
    const unsigned short* __restrict__ A, long long sAb, int lda,
    const unsigned short* __restrict__ B, long long sBb, int ldb,
    unsigned short* __restrict__ Cb_, long long sCb, int ldc,
    const float* __restrict__ u)
{
  __shared__ unsigned short As[4][8192];
  __shared__ unsigned short Bs[4][8192];
  const int tid = threadIdx.x;
  const int bz = blockIdx.z;
  const int lane = tid & 63, w = tid >> 6;
  const int wr = w >> 2, wc = w & 3;
  const int lr = lane & 15, lg = lane >> 4;
  const int csw = lr & 7;
  const int ko0 = (lg ^ csw) * 8;
  const int ko1 = ((4 + lg) ^ csw) * 8;

  const int rl = tid >> 3;
  const int gc = (tid & 7) ^ (rl & 7);
  const unsigned short* pA = A + (size_t)bz * sAb + (size_t)rl * lda + gc * 8;
  const unsigned short* pB = B + (size_t)bz * sBb + (size_t)rl * ldb + gc * 8;

  auto stageA = [&](int t, int h) {
    const unsigned short* s = pA + (size_t)h * 128 * lda + t * 64;
    unsigned short* d = &As[(2 * t + h) & 3][tid * 8];
    gll16(s, d);
    gll16(s + (size_t)64 * lda, d + 4096);
  };
  auto stageB = [&](int t, int h) {
    const unsigned short* s = pB + (size_t)h * 128 * ldb + t * 64;
    unsigned short* d = &Bs[(2 * t + h) & 3][tid * 8];
    gll16(s, d);
    gll16(s + (size_t)64 * ldb, d + 4096);
  };

  f32x4 acc[8][4];
  #pragma unroll
  for (int i = 0; i < 8; ++i)
    #pragma unroll
    for (int j = 0; j < 4; ++j) acc[i][j] = (f32x4){0.f, 0.f, 0.f, 0.f};

  stageA(0, 0); stageA(0, 1); stageB(0, 0); stageB(0, 1);
  stageB(1, 0); stageA(1, 0); stageA(1, 1);
  asm volatile("s_waitcnt vmcnt(6)" ::: "memory");
  __builtin_amdgcn_s_barrier();

  for (int t = 0; t < NT; ++t) {
    const unsigned short* sA = &As[(2 * t + wr) & 3][0];
    const unsigned short* sB = &Bs[(2 * t + (wc >> 1)) & 3][0];
    const int bc = (wc & 1) * 64;
    short8 af[4][2], bf0[2][2], bf1[2][2];

    #pragma unroll
    for (int mi = 0; mi < 4; ++mi) {
      af[mi][0] = *(const short8*)(sA + (mi * 16 + lr) * 64 + ko0);
      af[mi][1] = *(const short8*)(sA + (mi * 16 + lr) * 64 + ko1);
    }
    #pragma unroll
    for (int nj = 0; nj < 2; ++nj) {
      bf0[nj][0] = *(const short8*)(sB + (bc + nj * 16 + lr) * 64 + ko0);
      bf0[nj][1] = *(const short8*)(sB + (bc + nj * 16 + lr) * 64 + ko1);
    }
    if (t + 1 < NT) stageB(t + 1, 1);
    __builtin_amdgcn_s_barrier();
    __builtin_amdgcn_s_setprio(1);
    #pragma unroll
    for (int mi = 0; mi < 4; ++mi)
      #pragma unroll
      for (int nj = 0; nj < 2; ++nj) {
        acc[mi][nj] = __builtin_amdgcn_mfma_f32_16x16x32_bf16(af[mi][0], bf0[nj][0], acc[mi][nj], 0, 0, 0);
        acc[mi][nj] = __builtin_amdgcn_mfma_f32_16x16x32_bf16(af[mi][1], bf0[nj][1], acc[mi][nj], 0, 0, 0);
      }
    __builtin_amdgcn_s_setprio(0);
    __builtin_amdgcn_s_barrier();

    #pragma unroll
    for (int nj = 0; nj < 2; ++nj) {
      bf1[nj][0] = *(const short8*)(sB + (bc + 32 + nj * 16 + lr) * 64 + ko0);
      bf1[nj][1] = *(const short8*)(sB + (bc + 32 + nj * 16 + lr) * 64 + ko1);
    }
    __builtin_amdgcn_s_barrier();
    __builtin_amdgcn_s_setprio(1);
    #pragma unroll
    for (int mi = 0; mi < 4; ++mi)
      #pragma unroll
      for (int nj = 0; nj < 2; ++nj) {
        acc[mi][2 + nj] = __builtin_amdgcn_mfma_f32_16x16x32_bf16(af[mi][0], bf1[nj][0], acc[mi][2 + nj], 0, 0, 0);
        acc[mi][2 + nj] = __builtin_amdgcn_mfma_f32_16x16x32_bf16(af[mi][1], bf1[nj][1], acc[mi][2 + nj], 0, 0, 0);
      }
    __builtin_amdgcn_s_setprio(0);
    __builtin_amdgcn_s_barrier();

    #pragma unroll
    for (int mi = 0; mi < 4; ++mi) {
      af[mi][0] = *(const short8*)(sA + (64 + mi * 16 + lr) * 64 + ko0);
      af[mi][1] = *(const short8*)(sA + (64 + mi * 16 + lr) * 64 + ko1);
    }
    if (t + 2 < NT) stageB(t + 2, 0);
    __builtin_amdgcn_s_barrier();
    __builtin_amdgcn_s_setprio(1);
    #pragma unroll
    for (int mi = 0; mi < 4; ++mi)
      #pragma unroll
      for (int nj = 0; nj < 2; ++nj) {
        acc[4 + mi][nj] = __builtin_amdgcn_mfma_f32_16x16x32_bf16(af[mi][0], bf0[nj][0], acc[4 + mi][nj], 0, 0, 0);
        acc[4 + mi][nj] = __builtin_amdgcn_mfma_f32_16x16x32_bf16(af[mi][1], bf0[nj][1], acc[4 + mi][nj], 0, 0, 0);
      }
    __builtin_amdgcn_s_setprio(0);
    __builtin_amdgcn_s_barrier();

    if (t + 2 < NT) { stageA(t + 2, 0); stageA(t + 2, 1); }
    __builtin_amdgcn_s_barrier();
    __builtin_amdgcn_s_setprio(1);
    #pragma unroll
    for (int mi = 0; mi < 4; ++mi)
      #pragma unroll
      for (int nj = 0; nj < 2; ++nj) {
        acc[4 + mi][2 + nj] = __builtin_amdgcn_mfma_f32_16x16x32_bf16(af[mi][0], bf1[nj][0], acc[4 + mi][2 + nj], 0, 0, 0);
        acc[4 + mi][2 + nj] = __builtin_amdgcn_mfma_f32_16x16x32_bf16(af[mi][1], bf1[nj][1], acc[4 + mi][2 + nj], 0, 0, 0);
      }
    __builtin_amdgcn_s_setprio(0);
    if (t == NT - 2)      asm volatile("s_waitcnt vmcnt(0)" ::: "memory");
    else if (t < NT - 2)  asm volatile("s_waitcnt vmcnt(6)" ::: "memory");
    __builtin_amdgcn_s_barrier();
  }

  float uv[4];
  #pragma unroll
  for (int ni = 0; ni < 4; ++ni) uv[ni] = u[bz * 256 + wc * 64 + ni * 16 + lr];
  #pragma unroll
  for (int mi = 0; mi < 8; ++mi)
    #pragma unroll
    for (int ni = 0; ni < 4; ++ni)
      #pragma unroll
      for (int r = 0; r < 4; ++r) acc[mi][ni][r] += uv[ni];

  const float SC = 0.044194173824159216f;
  float* redm = (float*)&As[0][0];
  float* reds = redm + 1024;
  float rmax[8][4];
  #pragma unroll
  for (int mi = 0; mi < 8; ++mi)
    #pragma unroll
    for (int r = 0; r < 4; ++r) {
      float m = fmaxf(fmaxf(acc[mi][0][r], acc[mi][1][r]),
                      fmaxf(acc[mi][2][r], acc[mi][3][r]));
      #pragma unroll
      for (int o = 1; o <= 8; o <<= 1) m = fmaxf(m, __shfl_xor(m, o));
      rmax[mi][r] = m;
    }
  __syncthreads();
  if (lr == 0) {
    #pragma unroll
    for (int mi = 0; mi < 8; ++mi)
      #pragma unroll
      for (int r = 0; r < 4; ++r)
        redm[(wr * 128 + mi * 16 + lg * 4 + r) * 4 + wc] = rmax[mi][r];
  }
  __syncthreads();
  float rsum[8][4];
  #pragma unroll
  for (int mi = 0; mi < 8; ++mi)
    #pragma unroll
    for (int r = 0; r < 4; ++r) {
      const int row = wr * 128 + mi * 16 + lg * 4 + r;
      f32x4 q = *(const f32x4*)&redm[row * 4];
      const float m = fmaxf(fmaxf(q[0], q[1]), fmaxf(q[2], q[3]));
      float s = 0.f;
      #pragma unroll
      for (int ni = 0; ni < 4; ++ni) {
        float e = __expf((acc[mi][ni][r] - m) * SC);
        acc[mi][ni][r] = e;
        s += e;
      }
      #pragma unroll
      for (int o = 1; o <= 8; o <<= 1) s += __shfl_xor(s, o);
      rsum[mi][r] = s;
    }
  if (lr == 0) {
    #pragma unroll
    for (int mi = 0; mi < 8; ++mi)
      #pragma unroll
      for (int r = 0; r < 4; ++r)
        reds[(wr * 128 + mi * 16 + lg * 4 + r) * 4 + wc] = rsum[mi][r];
  }
  __syncthreads();
  unsigned short* Cb = Cb_ + (size_t)bz * sCb;
  #pragma unroll
  for (int mi = 0; mi < 8; ++mi)
    #pragma unroll
    for (int r = 0; r < 4; ++r) {
      const int row = wr * 128 + mi * 16 + lg * 4 + r;
      f32x4 q = *(const f32x4*)&reds[row * 4];
      const float inv = 1.f / (q[0] + q[1] + q[2] + q[3]);
      #pragma unroll
      for (int ni = 0; ni < 4; ++ni) {
        const int col = wc * 64 + ni * 16 + lr;
        Cb[(size_t)row * ldc + col] = f2bf(acc[mi][ni][r] * inv);
      }
    }
}

extern "C" void kernel_launch(void* const* d_in, const int* in_sizes, int n_in,
                              void* d_out, int out_size, void* d_ws, size_t ws_size,
                              hipStream_t stream)
{
  const float* x   = (const float*)d_in[0];
  const float* gnw = (const float*)d_in[1];
  const float* gnb = (const float*)d_in[2];
  const float* wq  = (const float*)d_in[3];
  const float* bq  = (const float*)d_in[4];
  const float* wk  = (const float*)d_in[5];
  // bk cancels in softmax
  const float* wv  = (const float*)d_in[7];
  const float* bv  = (const float*)d_in[8];
  const float* wp  = (const float*)d_in[9];
  const float* bp  = (const float*)d_in[10];
  float* out = (float*)d_out;

  char* ws = (char*)d_ws;
  unsigned short* W2T   = (unsigned short*)(ws);                  // [512][512] bf16
  unsigned short* wvb   = (unsigned short*)(ws + 524288);
  unsigned short* wpb   = (unsigned short*)(ws + 1048576);
  unsigned short* wqT   = (unsigned short*)(ws + 1572864);
  unsigned short* wkT   = (unsigned short*)(ws + 2097152);
  float*          w2b   = (float*)(ws + 2621440);
  float*          uflat = (float*)(ws + 2623488);
  unsigned short* hT    = (unsigned short*)(ws + 2885632);        // 65536x512 bf16 (reused as oT)
  unsigned short* T1    = (unsigned short*)(ws + 69994496ull);    // 65536x512 bf16
  unsigned short* v     = (unsigned short*)(ws + 137103360ull);   // B*512*256 bf16
  unsigned short* attb  = (unsigned short*)(ws + 204212224ull);   // B*256*256 bf16
  unsigned short* oT    = hT;

  conv_k<<<512, 256, 0, stream>>>(wv, wp, wvb, wpb);
  tk<<<dim3(8, 8, 2), 256, 0, stream>>>(wq, wk, wqT, wkT);
  w2b_k<<<8, 256, 0, stream>>>(wkT, bq, w2b);
  // W2T[d][c] = sum_o wk[o][d]*wq[o][c]
  gemmp_k<128, 128, 4, 256, 2, 8, 0, false, false, false><<<dim3(4, 4, 1), 256, 0, stream>>>(
      wkT, 0, 512, wqT, 0, 512, W2T, 0, 512, nullptr, nullptr);
  gn_k<<<4096, 512, 0, stream>>>(x, gnw, gnb, hT);
  gemv_u<<<16384, 256, 0, stream>>>(hT, w2b, uflat);
  // G1 (flat): T1[s][d] = hT x W2T^T  [65536 x 512 x 512]
  gemmp_k<256, 256, 8, 512, 4, 8, 0, false, false, true><<<dim3(2, 256, 1), 512, 0, stream>>>(
      hT, 0, 512, W2T, 0, 512, T1, 0, 512, nullptr, nullptr);
  // G1b (per-batch): v[b][c][s] = wvb x hT[b]^T + bv
  gemmp_k<128, 128, 4, 256, 2, 8, 1, false, false, false><<<dim3(4, 2, 256), 256, 0, stream>>>(
      wvb, 0, 512, hT, 131072, 512, v, 131072, 256, bv, nullptr);
  // G2+softmax: attb[b][s][t] = softmax_t((T1 hT^T + 1 u^T)/sqrt(512))
  gemm3_k<8><<<dim3(1, 1, 256), 512, 0, stream>>>(
      T1, 131072, 512, hT, 131072, 512, attb, 65536, 256, uflat);
  // G3 (per-batch): oT[b][t][c] = attb[b] x v[b]^T
  gemmp_k<128, 128, 4, 256, 2, 4, 0, false, false, false><<<dim3(2, 4, 256), 256, 0, stream>>>(
      attb, 65536, 256, v, 131072, 256, oT, 131072, 512, nullptr, nullptr);
  // G4 (per-batch): out[b][c][s] = wpb x oT[b]^T + bp + x
  gemmp_k<128, 128, 4, 256, 2, 8, 1, true, true, false><<<dim3(4, 2, 256), 256, 0, stream>>>(
      wpb, 0, 512, oT, 131072, 512, out, 131072, 256, bp, x);
}